// Round 7
// baseline (10887.417 us; speedup 1.0000x reference)
//
#include <hip/hip_runtime.h>
#include <hip/hip_fp16.h>

#define L_SEQ 2048
#define N_B   64
#define IN_K  128
#define MEM_N 256

typedef float    f32x4 __attribute__((ext_vector_type(4)));
typedef _Float16 f16x8 __attribute__((ext_vector_type(8)));
typedef unsigned u32x4 __attribute__((ext_vector_type(4)));

__device__ __forceinline__ float rcp_f(float x) { return __builtin_amdgcn_rcpf(x); }
__device__ __forceinline__ float tanh_f(float x) {
    return 1.0f - 2.0f * rcp_f(__expf(2.0f * x) + 1.0f);
}
__device__ __forceinline__ float sig_f(float x) {
    return rcp_f(1.0f + __expf(-x));
}

// split-f16: v ~= hi + lo with ~22-bit effective mantissa
__device__ __forceinline__ void split8(const float* v, f16x8& hi, f16x8& lo) {
#pragma unroll
    for (int i = 0; i < 8; ++i) {
        _Float16 h = (_Float16)v[i];
        hi[i] = h;
        lo[i] = (_Float16)(v[i] - (float)h);
    }
}

// 512 WGs launched, only blockIdx%8==0 real (64 WGs -> one XCD if dispatch is
// round-robin). rwg: group g=rwg&3 owns batches [16g,16g+16); slice s=rwg>>2
// owns rows [16s,16s+16). Weights in registers (split-f16, loaded once).
// Exchange: self-validating u64 slots {tag=t+1, payload=hf hi/lo f16}.
//   FAST (per-group, runtime-PROBED): plain store -> shared XCD L2; sc0 load.
//   SAFE (r6-proven): agent-relaxed atomic store; sc0 sc1 load (MALL).
// Probe = the exact fast-path instruction pair on scratch slots; 4 monotone
// rounds + XCC_ID uniformity. Any doubt -> SAFE. Both modes compute bitwise-
// identical results, so the mode choice never affects output.
__global__ void __launch_bounds__(256, 2)
befrc_scan(const float* __restrict__ u,
           const float* __restrict__ Wia, const float* __restrict__ Wha,
           const float* __restrict__ Wib, const float* __restrict__ Whb,
           const float* __restrict__ Wic, const float* __restrict__ Whc,
           const float* __restrict__ Wid, const float* __restrict__ Whd,
           const float* __restrict__ Wie, const float* __restrict__ Whe,
           const float* __restrict__ Wio,
           float* __restrict__ out,                    // [64][2048][256] f32 then [64][256] f32
           unsigned long long* __restrict__ pubq,      // [2][64][256] u64 (zeroed pre-launch)
           unsigned* __restrict__ ctrl,                // [64] u32 verdicts (zeroed)
           unsigned* __restrict__ probe)               // [64][16] u32 probe slots (zeroed)
{
    if (blockIdx.x & 7) return;        // dummies exit: real WGs co-located if %8 RR
    const int rwg = blockIdx.x >> 3;   // 0..63
    const int g   = rwg & 3;           // group 0..3
    const int s   = rwg >> 2;          // m-slice 0..15
    const int tid = threadIdx.x;       // 0..255
    const int w   = tid >> 6;          // wave 0..3
    const int l   = tid & 63;
    const int lq  = l >> 4;            // 0..3
    const int lr  = l & 15;            // 0..15

    // [gate][wave][b(col)][m(row)], inner dim padded 16->20 floats (4-way max)
    __shared__ __align__(16) float red[2][6][4][16][20];   // 60 KB
    __shared__ int s_fast;

    // ---- one-time coherence probe + group-uniform verdict ----
    unsigned xcc;
    asm volatile("s_getreg_b32 %0, hwreg(HW_REG_XCC_ID)" : "=s"(xcc));
    int ok = 1;
    {
        unsigned* myslot = probe + (unsigned)rwg * 16;
        const unsigned* peer = probe + (unsigned)(g + 4 * (l & 15)) * 16;
        for (int r = 1; r <= 4; ++r) {
            if (tid == 0)
                asm volatile("global_store_dword %0, %1, off"
                             :: "v"(myslot), "v"(r) : "memory");
            if (w == 0) {
                int good = 0;
                for (int it = 0; it < 2048; ++it) {
                    unsigned v;
                    asm volatile("global_load_dword %0, %1, off sc0\n\t"
                                 "s_waitcnt vmcnt(0)"
                                 : "=v"(v) : "v"(peer) : "memory");
                    if (__all((int)(l >= 16 || v >= (unsigned)r))) { good = 1; break; }
                }
                ok &= good;
            }
        }
    }
    if (tid == 0)
        __hip_atomic_store(&ctrl[rwg],
                           0x10000u | ((unsigned)(ok & 1) << 8) | (xcc & 0xffu),
                           __ATOMIC_RELEASE, __HIP_MEMORY_SCOPE_AGENT);
    if (w == 0) {
        unsigned v;
        for (;;) {   // all 64 real WGs are resident -> terminates
            v = __hip_atomic_load(&ctrl[g + 4 * (l & 15)],
                                  __ATOMIC_ACQUIRE, __HIP_MEMORY_SCOPE_AGENT);
            if (__all((int)((v & 0x10000u) != 0))) break;
            __builtin_amdgcn_s_sleep(2);
        }
        const unsigned ref = __builtin_amdgcn_readfirstlane(v);
        const int f = (__all((int)(v == ref)) && ((ref >> 8) & 1)) ? 1 : 0;
        if (tid == 0) s_fast = f;
    }
    __syncthreads();
    const bool fast = (s_fast != 0);

    const float* Wi[6] = {Wia, Wib, Wic, Wid, Wie, Wio};
    const float* Wh[5] = {Wha, Whb, Whc, Whd, Whe};

    // ---- preload weight fragments into registers, split-f16 (step-invariant) ----
    const int mrow = s * 16 + lr;
    f16x8 whf_hi[5][2], whf_lo[5][2];
#pragma unroll
    for (int gg = 0; gg < 5; ++gg) {
#pragma unroll
        for (int cc = 0; cc < 2; ++cc) {
            const int k0 = (2 * w + cc) * 32 + lq * 4;
            const float* p = Wh[gg] + mrow * MEM_N + k0;
            float4 f0 = *(const float4*)p;
            float4 f1 = *(const float4*)(p + 16);
            float v[8] = {f0.x, f0.y, f0.z, f0.w, f1.x, f1.y, f1.z, f1.w};
            split8(v, whf_hi[gg][cc], whf_lo[gg][cc]);
        }
    }
    f16x8 wif_hi[6], wif_lo[6];
#pragma unroll
    for (int gg = 0; gg < 6; ++gg) {
        const int k0 = w * 32 + lq * 4;
        const float* p = Wi[gg] + mrow * IN_K + k0;
        float4 f0 = *(const float4*)p;
        float4 f1 = *(const float4*)(p + 16);
        float v[8] = {f0.x, f0.y, f0.z, f0.w, f1.x, f1.y, f1.z, f1.w};
        split8(v, wif_hi[gg], wif_lo[gg]);
    }

    // pointwise-phase element mapping: one element per thread
    const int eb    = tid >> 4;          // batch col 0..15
    const int em    = tid & 15;          // m row local 0..15
    const int bglob = g * 16 + eb;
    const int mglob = s * 16 + em;
    float hf_loc = 0.0f, hs_loc = 0.0f, h_prev = 0.0f;

    const int  bfrag  = g * 16 + lr;                 // B-operand col = lane&15
    const long u_base = (long)bfrag * L_SEQ * IN_K + w * 32 + lq * 4;
    const int  k0a    = (2 * w + 0) * 32 + lq * 4;
    const int  k0b    = (2 * w + 1) * 32 + lq * 4;

    // prologue: issue u(0) prefetch (retired by step-0 poll's vmcnt(0))
    u32x4 ua, ub2;
    {
        const float* up = u + u_base;
        asm volatile(
            "global_load_dwordx4 %0, %2, off\n\t"
            "global_load_dwordx4 %1, %3, off"
            : "=v"(ua), "=v"(ub2)
            : "v"(up), "v"(up + 16)
            : "memory");
    }

    float* const out_row = out + (long)bglob * L_SEQ * MEM_N + mglob;

#pragma clang loop unroll(disable)
    for (int t = 0; t < L_SEQ; ++t) {
        // ---- B: poll the 16 self-validating slots this wave consumes ----
        u32x4 r0, r1, r2, r3, r4, r5, r6, r7;
        {
            const unsigned tgt = (unsigned)t;
            const unsigned long long* pb =
                pubq + (size_t)(t & 1) * N_B * MEM_N + (size_t)bfrag * MEM_N;
            const unsigned long long* p0 = pb + k0a;
            const unsigned long long* p1 = pb + k0a + 16;
            const unsigned long long* p2 = pb + k0b;
            const unsigned long long* p3 = pb + k0b + 16;
            int spins = 0;
            if (fast) {
                for (;;) {   // sc0-only: reads the shared XCD L2 (probe-verified)
                    asm volatile(
                        "global_load_dwordx4 %0, %8, off sc0\n\t"
                        "global_load_dwordx4 %1, %8, off offset:16 sc0\n\t"
                        "global_load_dwordx4 %2, %9, off sc0\n\t"
                        "global_load_dwordx4 %3, %9, off offset:16 sc0\n\t"
                        "global_load_dwordx4 %4, %10, off sc0\n\t"
                        "global_load_dwordx4 %5, %10, off offset:16 sc0\n\t"
                        "global_load_dwordx4 %6, %11, off sc0\n\t"
                        "global_load_dwordx4 %7, %11, off offset:16 sc0\n\t"
                        "s_waitcnt vmcnt(0)"
                        : "=v"(r0), "=v"(r1), "=v"(r2), "=v"(r3),
                          "=v"(r4), "=v"(r5), "=v"(r6), "=v"(r7)
                        : "v"(p0), "v"(p1), "v"(p2), "v"(p3)
                        : "memory");
                    int ok2 = (r0[1] == tgt) & (r0[3] == tgt) & (r1[1] == tgt) & (r1[3] == tgt)
                            & (r2[1] == tgt) & (r2[3] == tgt) & (r3[1] == tgt) & (r3[3] == tgt)
                            & (r4[1] == tgt) & (r4[3] == tgt) & (r5[1] == tgt) & (r5[3] == tgt)
                            & (r6[1] == tgt) & (r6[3] == tgt) & (r7[1] == tgt) & (r7[3] == tgt);
                    if (__all(ok2) || ++spins > (1 << 20)) break;
                }
            } else {
                for (;;) {   // system scope: proven against MALL (rounds 3/4/6)
                    asm volatile(
                        "global_load_dwordx4 %0, %8, off sc0 sc1\n\t"
                        "global_load_dwordx4 %1, %8, off offset:16 sc0 sc1\n\t"
                        "global_load_dwordx4 %2, %9, off sc0 sc1\n\t"
                        "global_load_dwordx4 %3, %9, off offset:16 sc0 sc1\n\t"
                        "global_load_dwordx4 %4, %10, off sc0 sc1\n\t"
                        "global_load_dwordx4 %5, %10, off offset:16 sc0 sc1\n\t"
                        "global_load_dwordx4 %6, %11, off sc0 sc1\n\t"
                        "global_load_dwordx4 %7, %11, off offset:16 sc0 sc1\n\t"
                        "s_waitcnt vmcnt(0)"
                        : "=v"(r0), "=v"(r1), "=v"(r2), "=v"(r3),
                          "=v"(r4), "=v"(r5), "=v"(r6), "=v"(r7)
                        : "v"(p0), "v"(p1), "v"(p2), "v"(p3)
                        : "memory");
                    int ok2 = (r0[1] == tgt) & (r0[3] == tgt) & (r1[1] == tgt) & (r1[3] == tgt)
                            & (r2[1] == tgt) & (r2[3] == tgt) & (r3[1] == tgt) & (r3[3] == tgt)
                            & (r4[1] == tgt) & (r4[3] == tgt) & (r5[1] == tgt) & (r5[3] == tgt)
                            & (r6[1] == tgt) & (r6[3] == tgt) & (r7[1] == tgt) & (r7[3] == tgt);
                    if (__all(ok2) || ++spins > (1 << 17)) break;
                }
            }
        }
        __builtin_amdgcn_sched_barrier(0);   // nothing below hoists above the poll

        // ---- G(prev): delayed out-store — full step for the HBM ack to retire ----
        if (t) out_row[(long)(t - 1) * MEM_N] = h_prev;

        // ---- A: input projections from prefetched u ----
        f32x4 acc[6];
#pragma unroll
        for (int gg = 0; gg < 6; ++gg) acc[gg] = (f32x4){0.f, 0.f, 0.f, 0.f};
        {
            float4 f0 = __builtin_bit_cast(float4, ua);
            float4 f1 = __builtin_bit_cast(float4, ub2);
            float v[8] = {f0.x, f0.y, f0.z, f0.w, f1.x, f1.y, f1.z, f1.w};
            f16x8 uh, ul;
            split8(v, uh, ul);
#pragma unroll
            for (int gg = 0; gg < 6; ++gg) {
                acc[gg] = __builtin_amdgcn_mfma_f32_16x16x32_f16(wif_hi[gg], uh, acc[gg], 0, 0, 0);
                acc[gg] = __builtin_amdgcn_mfma_f32_16x16x32_f16(wif_hi[gg], ul, acc[gg], 0, 0, 0);
                acc[gg] = __builtin_amdgcn_mfma_f32_16x16x32_f16(wif_lo[gg], uh, acc[gg], 0, 0, 0);
            }
        }

        // ---- B2: issue u(t+1) prefetch (retired by next step's poll) ----
        {
            const float* up = u + u_base + (long)((t + 1 < L_SEQ) ? t + 1 : t) * IN_K;
            asm volatile(
                "global_load_dwordx4 %0, %2, off\n\t"
                "global_load_dwordx4 %1, %3, off"
                : "=v"(ua), "=v"(ub2)
                : "v"(up), "v"(up + 16)
                : "memory");
        }

        // ---- C: unpack payloads + hidden matvecs ----
        unsigned pay[16] = {r0[0], r0[2], r1[0], r1[2], r2[0], r2[2], r3[0], r3[2],
                            r4[0], r4[2], r5[0], r5[2], r6[0], r6[2], r7[0], r7[2]};
#pragma unroll
        for (int cc = 0; cc < 2; ++cc) {
            f16x8 hb_hi, hb_lo;
#pragma unroll
            for (int j = 0; j < 8; ++j) {
                const unsigned p = pay[cc * 8 + j];
                hb_hi[j] = __builtin_bit_cast(_Float16, (unsigned short)(p & 0xffff));
                hb_lo[j] = __builtin_bit_cast(_Float16, (unsigned short)(p >> 16));
            }
#pragma unroll
            for (int gg = 0; gg < 5; ++gg) {
                acc[gg] = __builtin_amdgcn_mfma_f32_16x16x32_f16(whf_hi[gg][cc], hb_hi, acc[gg], 0, 0, 0);
                acc[gg] = __builtin_amdgcn_mfma_f32_16x16x32_f16(whf_hi[gg][cc], hb_lo, acc[gg], 0, 0, 0);
                acc[gg] = __builtin_amdgcn_mfma_f32_16x16x32_f16(whf_lo[gg][cc], hb_hi, acc[gg], 0, 0, 0);
            }
        }

        // ---- D: cross-wave partial exchange; raw lgkm-only barrier ----
        const int pb2 = t & 1;
#pragma unroll
        for (int gg = 0; gg < 6; ++gg)
            *(f32x4*)&red[pb2][gg][w][lr][lq * 4] = acc[gg];
        asm volatile("s_waitcnt lgkmcnt(0)\n\ts_barrier" ::: "memory");
        __builtin_amdgcn_sched_barrier(0);

        // ---- E: reduce hfn-relevant gates {a,b,c,o} first; publish early ----
        float pre0, pre1, pre2, pre5;
        pre0 = red[pb2][0][0][eb][em] + red[pb2][0][1][eb][em]
             + red[pb2][0][2][eb][em] + red[pb2][0][3][eb][em];
        pre1 = red[pb2][1][0][eb][em] + red[pb2][1][1][eb][em]
             + red[pb2][1][2][eb][em] + red[pb2][1][3][eb][em];
        pre2 = red[pb2][2][0][eb][em] + red[pb2][2][1][eb][em]
             + red[pb2][2][2][eb][em] + red[pb2][2][3][eb][em];
        pre5 = red[pb2][5][0][eb][em] + red[pb2][5][1][eb][em]
             + red[pb2][5][2][eb][em] + red[pb2][5][3][eb][em];

        const float hf_old = hf_loc, hs_old = hs_loc;
        {
            const float av  = 1.0f + tanh_f(pre0);
            const float bv  = 1.5f * (1.0f + tanh_f(pre1));
            const float cv  = 0.3f  + 0.7f * sig_f(pre2);     // 3*DT + (1-3*DT)*sig
            const float arg = pre5 + (av + bv * hf_old * hf_old - hs_old) * hf_old;
            hf_loc = (1.0f - cv) * hf_old + cv * tanh_f(arg);
        }
        {
            const _Float16 ph = (_Float16)hf_loc;
            const _Float16 pl = (_Float16)(hf_loc - (float)ph);
            const unsigned paw = (unsigned)__builtin_bit_cast(unsigned short, ph)
                               | ((unsigned)__builtin_bit_cast(unsigned short, pl) << 16);
            const unsigned long long val = ((unsigned long long)(unsigned)(t + 1) << 32) | paw;
            unsigned long long* pp = pubq + (size_t)((t + 1) & 1) * N_B * MEM_N
                                   + (size_t)bglob * MEM_N + mglob;
            if (fast) {   // plain store: write-through L1 -> shared XCD L2
                asm volatile("global_store_dwordx2 %0, %1, off"
                             :: "v"(pp), "v"(val) : "memory");
            } else {
                __hip_atomic_store(pp, val, __ATOMIC_RELAXED, __HIP_MEMORY_SCOPE_AGENT);
            }
        }

        // ---- F: hsn (peers don't need it) ----
        {
            const float pre3 = red[pb2][3][0][eb][em] + red[pb2][3][1][eb][em]
                             + red[pb2][3][2][eb][em] + red[pb2][3][3][eb][em];
            const float pre4 = red[pb2][4][0][eb][em] + red[pb2][4][1][eb][em]
                             + red[pb2][4][2][eb][em] + red[pb2][4][3][eb][em];
            const float dv  = 0.03f * sig_f(pre3);            // 0.3*DT*sig
            const float ev  = 1.0f + sig_f(pre4);
            const float eh  = ev * hf_old;
            const float eh2 = eh * eh;
            hs_loc = hs_old * (1.0f - dv) + dv * (eh2 * eh2);
        }
        h_prev = hf_loc;
    }

    // tail: last sequence element + final state (second output)
    out_row[(long)(L_SEQ - 1) * MEM_N] = hf_loc;
    out[(long)N_B * L_SEQ * MEM_N + (long)bglob * MEM_N + mglob] = hf_loc;
}

extern "C" void kernel_launch(void* const* d_in, const int* in_sizes, int n_in,
                              void* d_out, int out_size, void* d_ws, size_t ws_size,
                              hipStream_t stream) {
    (void)in_sizes; (void)n_in; (void)out_size; (void)ws_size;
    const float* u   = (const float*)d_in[0];
    const float* Wia = (const float*)d_in[1];
    const float* Wha = (const float*)d_in[2];
    const float* Wib = (const float*)d_in[3];
    const float* Whb = (const float*)d_in[4];
    const float* Wic = (const float*)d_in[5];
    const float* Whc = (const float*)d_in[6];
    const float* Wid = (const float*)d_in[7];
    const float* Whd = (const float*)d_in[8];
    const float* Wie = (const float*)d_in[9];
    const float* Whe = (const float*)d_in[10];
    const float* Wio = (const float*)d_in[11];

    float* out = (float*)d_out;
    unsigned long long* pubq = (unsigned long long*)d_ws;     // 262144 B
    unsigned* ctrl  = (unsigned*)((char*)d_ws + 262144);      // 256 B
    unsigned* probe = (unsigned*)((char*)d_ws + 262400);      // 4096 B

    // zero slot tags (tag 0 == step-0 expectation, payload 0 == hf0), ctrl
    // verdicts, and probe slots — every launch, deterministic, capture-safe
    hipMemsetAsync(d_ws, 0, 262144 + 256 + 4096, stream);

    befrc_scan<<<dim3(512), dim3(256), 0, stream>>>(
        u, Wia, Wha, Wib, Whb, Wic, Whc, Wid, Whd, Wie, Whe, Wio,
        out, pubq, ctrl, probe);
}

// Round 9
// 6300.925 us; speedup vs baseline: 1.7279x; 1.7279x over previous
//
#include <hip/hip_runtime.h>
#include <hip/hip_fp16.h>

#define L_SEQ 2048
#define N_B   64
#define IN_K  128
#define MEM_N 256

typedef float    f32x4 __attribute__((ext_vector_type(4)));
typedef _Float16 f16x8 __attribute__((ext_vector_type(8)));
typedef unsigned u32x4 __attribute__((ext_vector_type(4)));

__device__ __forceinline__ float rcp_f(float x) { return __builtin_amdgcn_rcpf(x); }
__device__ __forceinline__ float tanh_f(float x) {
    return 1.0f - 2.0f * rcp_f(__expf(2.0f * x) + 1.0f);
}
__device__ __forceinline__ float sig_f(float x) {
    return rcp_f(1.0f + __expf(-x));
}

// split-f16: v ~= hi + lo with ~22-bit effective mantissa
__device__ __forceinline__ void split8(const float* v, f16x8& hi, f16x8& lo) {
#pragma unroll
    for (int i = 0; i < 8; ++i) {
        _Float16 h = (_Float16)v[i];
        hi[i] = h;
        lo[i] = (_Float16)(v[i] - (float)h);
    }
}

// 512 WGs launched; real iff (b&7)<4 && (b>>3)<16 -> 64 real WGs.
// g = b&7 (batch group AND XCD id under %8 round-robin), s = b>>3 (m-slice).
// Each group's 16 WGs exchange ONLY among themselves -> per-group XCD-local.
// Exchange: self-validating u64 slots {tag=t+1, payload=hf hi/lo f16}.
//   FAST (per-group, runtime-PROBED with the exact op pair):
//        global_store_dwordx2 sc0  ->  shared XCD L2  ->  global_load sc0
//   SAFE (r6-proven): agent-relaxed atomic store -> sc0 sc1 load (HBM/MALL).
// Both modes produce bitwise-identical values; mode never affects output.
// All polls are full vmcnt(0) drains (r8 lesson: no in-flight reg loads).
__global__ void __launch_bounds__(256, 1)
befrc_scan(const float* __restrict__ u,
           const float* __restrict__ Wia, const float* __restrict__ Wha,
           const float* __restrict__ Wib, const float* __restrict__ Whb,
           const float* __restrict__ Wic, const float* __restrict__ Whc,
           const float* __restrict__ Wid, const float* __restrict__ Whd,
           const float* __restrict__ Wie, const float* __restrict__ Whe,
           const float* __restrict__ Wio,
           float* __restrict__ out,                    // [64][2048][256] f32 then [64][256] f32
           unsigned long long* __restrict__ pubq,      // [2][64][256] u64 (zeroed pre-launch)
           unsigned* __restrict__ ctrl,                // [68] u32 (zeroed pre-launch)
           unsigned* __restrict__ probe)               // [64][16] u32 (zeroed pre-launch)
{
    const int b = blockIdx.x;
    if ((b & 7) >= 4 || (b >> 3) >= 16) return;   // dummies exit
    const int g   = b & 7;            // group 0..3 == XCD id (if RR)
    const int s   = b >> 3;           // m-slice 0..15
    const int rwg = s * 4 + g;        // 0..63
    const int tid = threadIdx.x;      // 0..255
    const int w   = tid >> 6;         // wave 0..3
    const int l   = tid & 63;
    const int lq  = l >> 4;           // 0..3
    const int lr  = l & 15;           // 0..15

    // [buf][gate][wave][b(col)][m(row)], inner padded 16->20 (r6-proven)
    __shared__ __align__(16) float red[2][6][4][16][20];   // 60 KB
    __shared__ int s_fast;

    // ---- one-time per-group coherence probe (exact fast-path op pair) ----
    unsigned xcc;
    asm volatile("s_getreg_b32 %0, hwreg(HW_REG_XCC_ID)" : "=s"(xcc));
    int ok = 1;
    {
        unsigned* myslot = probe + (unsigned)rwg * 16;
        const unsigned* peer = probe + (unsigned)((l & 15) * 4 + g) * 16;
        for (int r = 1; r <= 4; ++r) {
            if (tid == 0)
                asm volatile("global_store_dword %0, %1, off sc0"
                             :: "v"(myslot), "v"(r) : "memory");
            if (w == 0) {
                int good = 0;
                for (int it = 0; it < 2048; ++it) {
                    unsigned v;
                    asm volatile("global_load_dword %0, %1, off sc0\n\t"
                                 "s_waitcnt vmcnt(0)"
                                 : "=v"(v) : "v"(peer) : "memory");
                    if (__all((int)(l >= 16 || v >= (unsigned)r))) { good = 1; break; }
                }
                ok &= good;
            }
        }
    }
    if (tid == 0)
        __hip_atomic_store(&ctrl[rwg],
                           0x10000u | ((unsigned)(ok & 1) << 8) | (xcc & 0xffu),
                           __ATOMIC_RELEASE, __HIP_MEMORY_SCOPE_AGENT);
    if (s == 0 && w == 0) {           // group aggregator
        unsigned v = 0; int spins = 0; int timeout = 0;
        for (;;) {                    // all 64 real WGs resident -> bounded anyway
            v = __hip_atomic_load(&ctrl[(l & 15) * 4 + g],
                                  __ATOMIC_ACQUIRE, __HIP_MEMORY_SCOPE_AGENT);
            if (__all((int)((v & 0x10000u) != 0))) break;
            if (++spins > (1 << 20)) { timeout = 1; break; }
            __builtin_amdgcn_s_sleep(2);
        }
        const unsigned ref = __builtin_amdgcn_readfirstlane(v);
        const int uni = (!timeout && __all((int)(v == ref)) && ((ref >> 8) & 1)) ? 1 : 0;
        if (tid == 0)
            __hip_atomic_store(&ctrl[64 + g], 0x10000u | (unsigned)uni,
                               __ATOMIC_RELEASE, __HIP_MEMORY_SCOPE_AGENT);
    }
    if (w == 0) {
        unsigned v;
        do {
            v = __hip_atomic_load(&ctrl[64 + g], __ATOMIC_ACQUIRE, __HIP_MEMORY_SCOPE_AGENT);
            if (!(v & 0x10000u)) __builtin_amdgcn_s_sleep(2);
        } while (!(v & 0x10000u));    // aggregator always writes
        if (tid == 0) s_fast = (int)(v & 1u);
    }
    __syncthreads();
    const bool fast = (s_fast != 0);  // group-uniform

    const float* Wi[6] = {Wia, Wib, Wic, Wid, Wie, Wio};
    const float* Wh[5] = {Wha, Whb, Whc, Whd, Whe};

    // ---- preload weight fragments into registers, split-f16 (step-invariant) ----
    const int mrow = s * 16 + lr;
    f16x8 whf_hi[5][2], whf_lo[5][2];
#pragma unroll
    for (int gg = 0; gg < 5; ++gg) {
#pragma unroll
        for (int cc = 0; cc < 2; ++cc) {
            const int k0 = (2 * w + cc) * 32 + lq * 4;
            const float* ptr = Wh[gg] + mrow * MEM_N + k0;
            float4 f0 = *(const float4*)ptr;
            float4 f1 = *(const float4*)(ptr + 16);
            float v[8] = {f0.x, f0.y, f0.z, f0.w, f1.x, f1.y, f1.z, f1.w};
            split8(v, whf_hi[gg][cc], whf_lo[gg][cc]);
        }
    }
    f16x8 wif_hi[6], wif_lo[6];
#pragma unroll
    for (int gg = 0; gg < 6; ++gg) {
        const int k0 = w * 32 + lq * 4;
        const float* ptr = Wi[gg] + mrow * IN_K + k0;
        float4 f0 = *(const float4*)ptr;
        float4 f1 = *(const float4*)(ptr + 16);
        float v[8] = {f0.x, f0.y, f0.z, f0.w, f1.x, f1.y, f1.z, f1.w};
        split8(v, wif_hi[gg], wif_lo[gg]);
    }

    // pointwise-phase element mapping: one element per thread
    const int eb    = tid >> 4;          // batch col 0..15
    const int em    = tid & 15;          // m row local 0..15
    const int bglob = g * 16 + eb;
    const int mglob = s * 16 + em;
    float hf_loc = 0.0f, hs_loc = 0.0f, h_prev = 0.0f;

    const int  bfrag  = g * 16 + lr;                 // B-operand col = lane&15
    const long u_base = (long)bfrag * L_SEQ * IN_K + w * 32 + lq * 4;
    const int  k0a    = (2 * w + 0) * 32 + lq * 4;
    const int  k0b    = (2 * w + 1) * 32 + lq * 4;

    // prologue: issue u(0) prefetch (retired by step-0 poll's vmcnt(0))
    u32x4 ua, ub2;
    {
        const float* up = u + u_base;
        asm volatile(
            "global_load_dwordx4 %0, %2, off\n\t"
            "global_load_dwordx4 %1, %3, off"
            : "=v"(ua), "=v"(ub2)
            : "v"(up), "v"(up + 16)
            : "memory");
    }

    float* const out_row = out + (long)bglob * L_SEQ * MEM_N + mglob;

#pragma clang loop unroll(disable)
    for (int t = 0; t < L_SEQ; ++t) {
        // ---- B: poll the 16 self-validating slots this wave consumes ----
        u32x4 r0, r1, r2, r3, r4, r5, r6, r7;
        {
            const unsigned tgt = (unsigned)t;
            const unsigned long long* pb =
                pubq + (size_t)(t & 1) * N_B * MEM_N + (size_t)bfrag * MEM_N;
            const unsigned long long* p0 = pb + k0a;
            const unsigned long long* p1 = pb + k0a + 16;
            const unsigned long long* p2 = pb + k0b;
            const unsigned long long* p3 = pb + k0b + 16;
            int spins = 0;
            if (fast) {
                for (;;) {   // sc0-only: shared XCD L2 (probe-verified pair)
                    asm volatile(
                        "global_load_dwordx4 %0, %8, off sc0\n\t"
                        "global_load_dwordx4 %1, %8, off offset:16 sc0\n\t"
                        "global_load_dwordx4 %2, %9, off sc0\n\t"
                        "global_load_dwordx4 %3, %9, off offset:16 sc0\n\t"
                        "global_load_dwordx4 %4, %10, off sc0\n\t"
                        "global_load_dwordx4 %5, %10, off offset:16 sc0\n\t"
                        "global_load_dwordx4 %6, %11, off sc0\n\t"
                        "global_load_dwordx4 %7, %11, off offset:16 sc0\n\t"
                        "s_waitcnt vmcnt(0)"
                        : "=v"(r0), "=v"(r1), "=v"(r2), "=v"(r3),
                          "=v"(r4), "=v"(r5), "=v"(r6), "=v"(r7)
                        : "v"(p0), "v"(p1), "v"(p2), "v"(p3)
                        : "memory");
                    int ok2 = (r0[1] == tgt) & (r0[3] == tgt) & (r1[1] == tgt) & (r1[3] == tgt)
                            & (r2[1] == tgt) & (r2[3] == tgt) & (r3[1] == tgt) & (r3[3] == tgt)
                            & (r4[1] == tgt) & (r4[3] == tgt) & (r5[1] == tgt) & (r5[3] == tgt)
                            & (r6[1] == tgt) & (r6[3] == tgt) & (r7[1] == tgt) & (r7[3] == tgt);
                    if (__all(ok2) || ++spins > (1 << 20)) break;
                }
            } else {
                for (;;) {   // system scope: r6-proven against MALL/HBM
                    asm volatile(
                        "global_load_dwordx4 %0, %8, off sc0 sc1\n\t"
                        "global_load_dwordx4 %1, %8, off offset:16 sc0 sc1\n\t"
                        "global_load_dwordx4 %2, %9, off sc0 sc1\n\t"
                        "global_load_dwordx4 %3, %9, off offset:16 sc0 sc1\n\t"
                        "global_load_dwordx4 %4, %10, off sc0 sc1\n\t"
                        "global_load_dwordx4 %5, %10, off offset:16 sc0 sc1\n\t"
                        "global_load_dwordx4 %6, %11, off sc0 sc1\n\t"
                        "global_load_dwordx4 %7, %11, off offset:16 sc0 sc1\n\t"
                        "s_waitcnt vmcnt(0)"
                        : "=v"(r0), "=v"(r1), "=v"(r2), "=v"(r3),
                          "=v"(r4), "=v"(r5), "=v"(r6), "=v"(r7)
                        : "v"(p0), "v"(p1), "v"(p2), "v"(p3)
                        : "memory");
                    int ok2 = (r0[1] == tgt) & (r0[3] == tgt) & (r1[1] == tgt) & (r1[3] == tgt)
                            & (r2[1] == tgt) & (r2[3] == tgt) & (r3[1] == tgt) & (r3[3] == tgt)
                            & (r4[1] == tgt) & (r4[3] == tgt) & (r5[1] == tgt) & (r5[3] == tgt)
                            & (r6[1] == tgt) & (r6[3] == tgt) & (r7[1] == tgt) & (r7[3] == tgt);
                    if (__all(ok2) || ++spins > (1 << 17)) break;
                }
            }
        }
        __builtin_amdgcn_sched_barrier(0);   // nothing below hoists above the poll

        // ---- G(prev): delayed out-store — full step for the HBM ack to retire ----
        if (t) out_row[(long)(t - 1) * MEM_N] = h_prev;

        // ---- A: input projections from prefetched u ----
        f32x4 acc[6];
#pragma unroll
        for (int gg = 0; gg < 6; ++gg) acc[gg] = (f32x4){0.f, 0.f, 0.f, 0.f};
        {
            float4 f0 = __builtin_bit_cast(float4, ua);
            float4 f1 = __builtin_bit_cast(float4, ub2);
            float v[8] = {f0.x, f0.y, f0.z, f0.w, f1.x, f1.y, f1.z, f1.w};
            f16x8 uh, ul;
            split8(v, uh, ul);
#pragma unroll
            for (int gg = 0; gg < 6; ++gg) {
                acc[gg] = __builtin_amdgcn_mfma_f32_16x16x32_f16(wif_hi[gg], uh, acc[gg], 0, 0, 0);
                acc[gg] = __builtin_amdgcn_mfma_f32_16x16x32_f16(wif_hi[gg], ul, acc[gg], 0, 0, 0);
                acc[gg] = __builtin_amdgcn_mfma_f32_16x16x32_f16(wif_lo[gg], uh, acc[gg], 0, 0, 0);
            }
        }

        // ---- B2: issue u(t+1) prefetch (retired by next step's poll) ----
        {
            const float* up = u + u_base + (long)((t + 1 < L_SEQ) ? t + 1 : t) * IN_K;
            asm volatile(
                "global_load_dwordx4 %0, %2, off\n\t"
                "global_load_dwordx4 %1, %3, off"
                : "=v"(ua), "=v"(ub2)
                : "v"(up), "v"(up + 16)
                : "memory");
        }

        // ---- C: unpack payloads + hidden matvecs ----
        unsigned pay[16] = {r0[0], r0[2], r1[0], r1[2], r2[0], r2[2], r3[0], r3[2],
                            r4[0], r4[2], r5[0], r5[2], r6[0], r6[2], r7[0], r7[2]};
#pragma unroll
        for (int cc = 0; cc < 2; ++cc) {
            f16x8 hb_hi, hb_lo;
#pragma unroll
            for (int j = 0; j < 8; ++j) {
                const unsigned pv = pay[cc * 8 + j];
                hb_hi[j] = __builtin_bit_cast(_Float16, (unsigned short)(pv & 0xffff));
                hb_lo[j] = __builtin_bit_cast(_Float16, (unsigned short)(pv >> 16));
            }
#pragma unroll
            for (int gg = 0; gg < 5; ++gg) {
                acc[gg] = __builtin_amdgcn_mfma_f32_16x16x32_f16(whf_hi[gg][cc], hb_hi, acc[gg], 0, 0, 0);
                acc[gg] = __builtin_amdgcn_mfma_f32_16x16x32_f16(whf_hi[gg][cc], hb_lo, acc[gg], 0, 0, 0);
                acc[gg] = __builtin_amdgcn_mfma_f32_16x16x32_f16(whf_lo[gg][cc], hb_hi, acc[gg], 0, 0, 0);
            }
        }

        // ---- D: cross-wave partial exchange; raw lgkm-only barrier ----
        const int pb2 = t & 1;
#pragma unroll
        for (int gg = 0; gg < 6; ++gg)
            *(f32x4*)&red[pb2][gg][w][lr][lq * 4] = acc[gg];
        asm volatile("s_waitcnt lgkmcnt(0)\n\ts_barrier" ::: "memory");
        __builtin_amdgcn_sched_barrier(0);

        // ---- E: reduce hfn-relevant gates {a,b,c,o} first; publish early ----
        const float pre0 = red[pb2][0][0][eb][em] + red[pb2][0][1][eb][em]
                         + red[pb2][0][2][eb][em] + red[pb2][0][3][eb][em];
        const float pre1 = red[pb2][1][0][eb][em] + red[pb2][1][1][eb][em]
                         + red[pb2][1][2][eb][em] + red[pb2][1][3][eb][em];
        const float pre2 = red[pb2][2][0][eb][em] + red[pb2][2][1][eb][em]
                         + red[pb2][2][2][eb][em] + red[pb2][2][3][eb][em];
        const float pre5 = red[pb2][5][0][eb][em] + red[pb2][5][1][eb][em]
                         + red[pb2][5][2][eb][em] + red[pb2][5][3][eb][em];

        const float hf_old = hf_loc, hs_old = hs_loc;
        {
            const float av  = 1.0f + tanh_f(pre0);
            const float bv  = 1.5f * (1.0f + tanh_f(pre1));
            const float cv  = 0.3f  + 0.7f * sig_f(pre2);     // 3*DT + (1-3*DT)*sig
            const float arg = pre5 + (av + bv * hf_old * hf_old - hs_old) * hf_old;
            hf_loc = (1.0f - cv) * hf_old + cv * tanh_f(arg);
        }
        {
            const _Float16 ph = (_Float16)hf_loc;
            const _Float16 pl = (_Float16)(hf_loc - (float)ph);
            const unsigned paw = (unsigned)__builtin_bit_cast(unsigned short, ph)
                               | ((unsigned)__builtin_bit_cast(unsigned short, pl) << 16);
            const unsigned long long val = ((unsigned long long)(unsigned)(t + 1) << 32) | paw;
            unsigned long long* pp = pubq + (size_t)((t + 1) & 1) * N_B * MEM_N
                                   + (size_t)bglob * MEM_N + mglob;
            if (fast) {   // sc0 store: write-through L1 -> shared XCD L2
                asm volatile("global_store_dwordx2 %0, %1, off sc0"
                             :: "v"(pp), "v"(val) : "memory");
            } else {
                __hip_atomic_store(pp, val, __ATOMIC_RELAXED, __HIP_MEMORY_SCOPE_AGENT);
            }
        }

        // ---- F: hsn (peers don't need it) ----
        {
            const float pre3 = red[pb2][3][0][eb][em] + red[pb2][3][1][eb][em]
                             + red[pb2][3][2][eb][em] + red[pb2][3][3][eb][em];
            const float pre4 = red[pb2][4][0][eb][em] + red[pb2][4][1][eb][em]
                             + red[pb2][4][2][eb][em] + red[pb2][4][3][eb][em];
            const float dv  = 0.03f * sig_f(pre3);            // 0.3*DT*sig
            const float ev  = 1.0f + sig_f(pre4);
            const float eh  = ev * hf_old;
            const float eh2 = eh * eh;
            hs_loc = hs_old * (1.0f - dv) + dv * (eh2 * eh2);
        }
        h_prev = hf_loc;
    }

    // tail: last sequence element + final state (second output)
    out_row[(long)(L_SEQ - 1) * MEM_N] = hf_loc;
    out[(long)N_B * L_SEQ * MEM_N + (long)bglob * MEM_N + mglob] = hf_loc;
}

extern "C" void kernel_launch(void* const* d_in, const int* in_sizes, int n_in,
                              void* d_out, int out_size, void* d_ws, size_t ws_size,
                              hipStream_t stream) {
    (void)in_sizes; (void)n_in; (void)out_size; (void)ws_size;
    const float* u   = (const float*)d_in[0];
    const float* Wia = (const float*)d_in[1];
    const float* Wha = (const float*)d_in[2];
    const float* Wib = (const float*)d_in[3];
    const float* Whb = (const float*)d_in[4];
    const float* Wic = (const float*)d_in[5];
    const float* Whc = (const float*)d_in[6];
    const float* Wid = (const float*)d_in[7];
    const float* Whd = (const float*)d_in[8];
    const float* Wie = (const float*)d_in[9];
    const float* Whe = (const float*)d_in[10];
    const float* Wio = (const float*)d_in[11];

    float* out = (float*)d_out;
    unsigned long long* pubq = (unsigned long long*)d_ws;     // 262144 B
    unsigned* ctrl  = (unsigned*)((char*)d_ws + 262144);      // 68 u32 (512 B pad)
    unsigned* probe = (unsigned*)((char*)d_ws + 262656);      // 4096 B

    // zero slot tags (tag 0 == step-0 expectation, payload 0 == hf0), ctrl,
    // probe — every launch, deterministic, graph-capture safe
    hipMemsetAsync(d_ws, 0, 262144 + 512 + 4096, stream);

    befrc_scan<<<dim3(512), dim3(256), 0, stream>>>(
        u, Wia, Wha, Wib, Whb, Wic, Whc, Wid, Whd, Wie, Whe, Wio,
        out, pubq, ctrl, probe);
}